// Round 6
// baseline (220.165 us; speedup 1.0000x reference)
//
#include <hip/hip_runtime.h>
#include <math.h>

#define NTOK 16384
#define KDIM 2048
#define NEXP 64
#define NW   16
#define BLOCK (NW * 64)          // 1024 threads, 16 waves
#define KS   (KDIM / NW)         // 128 k per wave
#define RPAD 68                  // padded row stride for reduce buffer

typedef float f2 __attribute__((ext_vector_type(2)));
typedef float f4 __attribute__((ext_vector_type(4)));

// Block: 64 rows x 64 experts, K split x16 across waves (LDS tree reduce).
// Wave-internal outer product: lane = (row-slot rs = lane>>2) x (expert-slot
// es = lane&3). Lane owns rows rs*4..rs*4+3 and experts e0*16..e0*16+15, so
// both x and w are per-lane VGPR data (no uniform-fetch serialization), and
// accumulators are f2 pairs -> v_pk_fma_f32 (packed fp32 = 2x issue rate).
__global__ __launch_bounds__(BLOCK, 4) void gate_main(
    const float* __restrict__ x, const float* __restrict__ gw,
    const float* __restrict__ gb, float* __restrict__ out_w,
    float* __restrict__ out_idx, float* __restrict__ ws)
{
    __shared__ float red[2 * 64 * RPAD];   // reduce slots / logit tile / probs
    __shared__ float meta[64 * 4];         // per-row {i1, i2, w1, w2}
    __shared__ float scnt[NEXP];           // per-expert selection counts

    const int tid   = threadIdx.x;
    const int lane  = tid & 63;
    const int wid   = __builtin_amdgcn_readfirstlane(tid >> 6);
    const int es    = lane & 3;        // expert slot: e0 = es*16
    const int rs    = lane >> 2;       // row slot:    r0 = rs*4
    const int e0    = es * 16;
    const int rbase = blockIdx.x * 64;
    const int k0    = wid * KS;

    const float* xbase = x + (size_t)(rbase + rs * 4) * KDIM + k0;
    const float* wrow0 = gw + (size_t)k0 * NEXP + e0;

    f2 a[4][8];                        // a[i][p] = row r0+i, experts e0+2p..+1
#pragma unroll
    for (int i = 0; i < 4; ++i)
#pragma unroll
        for (int p = 0; p < 8; ++p) a[i][p] = (f2){0.f, 0.f};

    // prologue: w row k0, x chunk 0 (4 rows)
    f4 w0 = *(const f4*)(wrow0 + 0);
    f4 w1 = *(const f4*)(wrow0 + 4);
    f4 w2 = *(const f4*)(wrow0 + 8);
    f4 w3 = *(const f4*)(wrow0 + 12);
    f4 x0 = *(const f4*)(xbase + 0 * (size_t)KDIM);
    f4 x1 = *(const f4*)(xbase + 1 * (size_t)KDIM);
    f4 x2 = *(const f4*)(xbase + 2 * (size_t)KDIM);
    f4 x3 = *(const f4*)(xbase + 3 * (size_t)KDIM);

    for (int c = 0; c < KS / 4; ++c) {
        const int cn = (c + 1 < KS / 4) ? c + 1 : c;   // clamped x prefetch
        f4 nx0 = *(const f4*)(xbase + 0 * (size_t)KDIM + cn * 4);
        f4 nx1 = *(const f4*)(xbase + 1 * (size_t)KDIM + cn * 4);
        f4 nx2 = *(const f4*)(xbase + 2 * (size_t)KDIM + cn * 4);
        f4 nx3 = *(const f4*)(xbase + 3 * (size_t)KDIM + cn * 4);
#pragma unroll
        for (int j = 0; j < 4; ++j) {
            const int k  = c * 4 + j;
            const int kn = (k + 1 < KS) ? k + 1 : k;   // clamped w prefetch
            const f2 xs0 = {x0[j], x0[j]};
            const f2 xs1 = {x1[j], x1[j]};
            const f2 xs2 = {x2[j], x2[j]};
            const f2 xs3 = {x3[j], x3[j]};
#pragma unroll
            for (int p = 0; p < 8; ++p) {
                const f4 cc = (p >> 1) == 0 ? w0 : (p >> 1) == 1 ? w1
                            : (p >> 1) == 2 ? w2 : w3;
                // element access (constant after unroll) instead of
                // __builtin_shufflevector, which demands literal indices
                const f2 wl = {cc[2 * (p & 1)], cc[2 * (p & 1) + 1]};
                a[0][p] = __builtin_elementwise_fma(xs0, wl, a[0][p]);
                a[1][p] = __builtin_elementwise_fma(xs1, wl, a[1][p]);
                a[2][p] = __builtin_elementwise_fma(xs2, wl, a[2][p]);
                a[3][p] = __builtin_elementwise_fma(xs3, wl, a[3][p]);
            }
            // reload w for k+1 (consumed next j; compiler may hoist)
            const float* wn = gw + (size_t)(k0 + kn) * NEXP + e0;
            w0 = *(const f4*)(wn + 0);
            w1 = *(const f4*)(wn + 4);
            w2 = *(const f4*)(wn + 8);
            w3 = *(const f4*)(wn + 12);
        }
        x0 = nx0; x1 = nx1; x2 = nx2; x3 = nx3;
    }

    // ---- pairwise tree reduce of 16 k-partials via 2 LDS slots ----
    // flat order: f4 #q = { a[q>>2][(q&3)*2], a[q>>2][(q&3)*2+1] }
    for (int half = NW / 2; half >= 1; half >>= 1) {
        for (int sub = 0; sub < half; sub += 2) {
            const int nslot = (half - sub < 2) ? (half - sub) : 2;
            __syncthreads();
            if (wid >= half + sub && wid < half + sub + nslot) {
                float* dst = red + (size_t)(wid - half - sub) * 64 * RPAD + lane * RPAD;
#pragma unroll
                for (int q = 0; q < 16; ++q) {
                    f4 v = {a[q >> 2][(q & 3) * 2].x,     a[q >> 2][(q & 3) * 2].y,
                            a[q >> 2][(q & 3) * 2 + 1].x, a[q >> 2][(q & 3) * 2 + 1].y};
                    *(f4*)(dst + q * 4) = v;
                }
            }
            __syncthreads();
            if (wid >= sub && wid < sub + nslot) {
                const float* src = red + (size_t)(wid - sub) * 64 * RPAD + lane * RPAD;
#pragma unroll
                for (int q = 0; q < 16; ++q) {
                    f4 v = *(const f4*)(src + q * 4);
                    a[q >> 2][(q & 3) * 2].x     += v.x;
                    a[q >> 2][(q & 3) * 2].y     += v.y;
                    a[q >> 2][(q & 3) * 2 + 1].x += v.z;
                    a[q >> 2][(q & 3) * 2 + 1].y += v.w;
                }
            }
        }
    }

    // ---- wave 0: transpose outer-product layout -> row-major tile in LDS ----
    __syncthreads();
    if (wid == 0) {
#pragma unroll
        for (int i = 0; i < 4; ++i)
#pragma unroll
            for (int p = 0; p < 8; ++p)
                *(f2*)(red + (size_t)(rs * 4 + i) * RPAD + e0 + 2 * p) = a[i][p];
    }
    __syncthreads();

    // ---- epilogue: wave 0, lane = row (identical to round-3 logic) ----
    int i1 = 0, i2 = 0;
    if (wid == 0) {
        float lg[64];
#pragma unroll
        for (int q = 0; q < 16; ++q) {
            f4 v = *(const f4*)(red + (size_t)lane * RPAD + q * 4);
            lg[q * 4 + 0] = v.x; lg[q * 4 + 1] = v.y;
            lg[q * 4 + 2] = v.z; lg[q * 4 + 3] = v.w;
        }
#pragma unroll
        for (int e = 0; e < NEXP; ++e) lg[e] += gb[e];

        // top-1 then top-2; strict > keeps lowest index on ties (lax.top_k)
        float v1 = lg[0];
#pragma unroll
        for (int e = 1; e < NEXP; ++e)
            if (lg[e] > v1) { v1 = lg[e]; i1 = e; }
        float v2 = -INFINITY;
#pragma unroll
        for (int e = 0; e < NEXP; ++e)
            if (e != i1 && lg[e] > v2) { v2 = lg[e]; i2 = e; }

        // full softmax (aux loss): probs overwrite this lane's tile row
        float ssum = 0.f;
#pragma unroll
        for (int e = 0; e < NEXP; ++e) ssum += __expf(lg[e] - v1);
        const float sinv = 1.f / ssum;
        float* pr = red + (size_t)lane * RPAD;
#pragma unroll
        for (int e = 0; e < NEXP; ++e) pr[e] = __expf(lg[e] - v1) * sinv;

        // renormalized top-2 softmax weights
        const float e2 = __expf(v2 - v1);
        const float wa = 1.f / (1.f + e2);
        f4 m = {(float)i1, (float)i2, wa, e2 * wa};
        ((f4*)meta)[lane] = m;

        *(float2*)(out_idx + (size_t)(rbase + lane) * 2) =
            make_float2((float)i1, (float)i2);

        scnt[lane] = 0.f;
        atomicAdd(&scnt[i1], 1.f);
        atomicAdd(&scnt[i2], 1.f);
    }
    __syncthreads();
    if (wid == 0) {
        // per-expert prob column-sum over this block's 64 rows (lane = expert)
        float ps = 0.f;
#pragma unroll
        for (int r = 0; r < 64; ++r) ps += red[(size_t)r * RPAD + lane];
        atomicAdd(&ws[lane], ps);
        atomicAdd(&ws[NEXP + lane], scnt[lane]);
    }
    __syncthreads();

    // ---- gate-weight store: each wave writes 4 rows, coalesced ----
#pragma unroll
    for (int rr = 0; rr < 4; ++rr) {
        const int r = wid * 4 + rr;
        const f4 m = ((const f4*)meta)[r];      // broadcast read
        const float val = (lane == (int)m.x) ? m.z
                        : ((lane == (int)m.y) ? m.w : 0.f);
        out_w[((size_t)rbase + r) * NEXP + lane] = val;
    }
}

__global__ void gate_aux(const float* __restrict__ ws, float* __restrict__ out_aux)
{
    const int e = threadIdx.x;  // 64 threads
    const float frac = ws[NEXP + e] * (1.f / (float)(NTOK * 2));
    const float mp   = ws[e] * (1.f / (float)NTOK);
    float v = frac * mp * (float)NEXP;
#pragma unroll
    for (int off = 32; off; off >>= 1) v += __shfl_xor(v, off);
    if (e == 0) out_aux[0] = v;
}

extern "C" void kernel_launch(void* const* d_in, const int* in_sizes, int n_in,
                              void* d_out, int out_size, void* d_ws, size_t ws_size,
                              hipStream_t stream) {
    const float* x  = (const float*)d_in[0];
    const float* gw = (const float*)d_in[1];
    const float* gb = (const float*)d_in[2];

    float* out     = (float*)d_out;
    float* out_w   = out;                         // [16384*64]
    float* out_idx = out + (size_t)NTOK * NEXP;   // [16384*2] as floats
    float* out_aux = out_idx + (size_t)NTOK * 2;  // [1]
    float* ws      = (float*)d_ws;                // [128] floats

    (void)hipMemsetAsync(ws, 0, 2 * NEXP * sizeof(float), stream);
    gate_main<<<NTOK / 64, BLOCK, 0, stream>>>(x, gw, gb, out_w, out_idx, ws);
    gate_aux<<<1, 64, 0, stream>>>(ws, out_aux);
}